// Round 10
// baseline (105.985 us; speedup 1.0000x reference)
//
#include <hip/hip_runtime.h>
#include <math.h>

// Problem constants (from reference)
#define BB 4
#define HH 512
#define WW 512
#define CC 32      // channels; 32 floats = 8 float4 = 128 B per point
#define HO 256
#define WO 256

#define MAXOCC 96   // shared-col slots incl sentinel slot 0; real slots 1..95
#define OVFCAP 104  // max shared-col cells = 33 cols x 3 rows = 99

// Fill index grid with zeros (0 == empty). int4-vectorized.
__global__ void fill_zero_kernel(int4* __restrict__ g, int n4) {
    int i = blockIdx.x * blockDim.x + threadIdx.x;
    if (i < n4) g[i] = make_int4(0, 0, 0, 0);
}

// Scatter point index+1 into dense (B,H,W) int grid.
__global__ void scatter_idx_kernel(const int* __restrict__ coors,
                                   int* __restrict__ grid, int n) {
    int i = blockIdx.x * blockDim.x + threadIdx.x;
    if (i >= n) return;
    int b = coors[i * 3 + 0];
    int y = coors[i * 3 + 1];
    int x = coors[i * 3 + 2];
    grid[((size_t)b * HH + y) * WW + x] = i + 1;
}

// Block = 32 ox x 1 oy x 8 cg. Window = 3 rows x 65 cols = 195 cells.
// Window structure (stride 2, width 3): side columns (local col even) are
// shared by 2 outputs -> staged through LDS (slot 0 = -inf sentinel);
// center columns (local col odd) are used by exactly 1 output -> direct
// branchless global gather (no LDS round-trip). Cuts LDS traffic ~30%.
__global__ void __launch_bounds__(256, 8)
pool_kernel(const float4* __restrict__ feat,   // N x 8 float4
            const int* __restrict__ grid,      // B*H*W
            float4* __restrict__ out) {        // B*HO*WO x 8 float4
    // blockIdx.x: [b(2b) | oy(8b) | ox_tile(3b)]
    int ox_base = (blockIdx.x & 7) * 32;
    int oy      = (blockIdx.x >> 3) & (HO - 1);
    int b       = blockIdx.x >> 11;

    int tid  = threadIdx.x;
    int lane = tid & 63;
    int cg   = tid & 7;         // channel group 0..7
    int p    = tid >> 3;        // local position 0..31

    int iy0 = 2 * oy - 1;
    int gx0 = 2 * ox_base - 1;
    const int* gb = grid + (size_t)b * (HH * WW);

    __shared__ int    cnt;
    __shared__ int    smap[3 * 65];        // >0 slot | 0 empty | <0 direct(-v)
    __shared__ int    srcidx[MAXOCC];      // slot -> point index (1..95)
    __shared__ float4 sfeat[MAXOCC * 8];   // swizzled: [s*8 + ((cg+s)&7)]
    __shared__ int    ovf_c[OVFCAP];       // overflow shared-cell id
    __shared__ int    ovf_i[OVFCAP];       // overflow point index

    const float NEG = -INFINITY;
    if (tid == 0) cnt = 0;
    if (tid < 8) sfeat[tid] = make_float4(NEG, NEG, NEG, NEG);  // sentinel s=0
    __syncthreads();

    // ---- Pass A: grid load; shared cols -> ballot slot compaction,
    //              center cols -> direct marker
    {
        int v = 0, c = 0;
        if (tid < 195) {
            int r = tid / 65;
            c = tid - r * 65;
            int iy = iy0 + r;
            int gx = gx0 + c;
            if ((unsigned)iy < (unsigned)HH && (unsigned)gx < (unsigned)WW)
                v = gb[iy * WW + gx];
        }
        bool shared_cell = (v != 0) && ((c & 1) == 0);
        unsigned long long mask = __ballot(shared_cell);
        int nz = (int)__popcll(mask);
        int base = 0;
        if (lane == 0 && nz) base = atomicAdd(&cnt, nz);
        base = __shfl(base, 0);
        int s = 1 + base + (int)__popcll(mask & ((1ull << lane) - 1ull));
        if (tid < 195) {
            int m = 0;
            if (v != 0) {
                if ((c & 1) != 0) {
                    m = -v;                      // center col: direct gather
                } else if (s < MAXOCC) {
                    srcidx[s] = v - 1; m = s;
                } else {
                    int o = s - MAXOCC;          // overflow (cnt>95, ~never)
                    ovf_c[o] = tid;
                    ovf_i[o] = v - 1;
                }
            }
            smap[tid] = m;
        }
    }
    __syncthreads();

    // ---- Pass B: stage shared-col occupied rows (slots 1..min(cnt,95))
    int hi = cnt < (MAXOCC - 1) ? cnt : (MAXOCC - 1);
    for (int s = 1 + (tid >> 3); s <= hi; s += 32)
        sfeat[(s << 3) + ((cg + s) & 7)] = feat[(size_t)srcidx[s] * 8 + cg];
    __syncthreads();

    // ---- Pass C: read 9 map entries; issue 3 direct global loads early;
    //              6 LDS reads (sentinel for empty); fold.
    int lc = 2 * p;             // window cols lc(shared), lc+1(center), lc+2(shared)
    int m[9];
#pragma unroll
    for (int r = 0; r < 3; ++r) {
        m[r * 3 + 0] = smap[r * 65 + lc + 0];
        m[r * 3 + 1] = smap[r * 65 + lc + 1];
        m[r * 3 + 2] = smap[r * 65 + lc + 2];
    }

    // direct loads for the 3 center cells (branchless: clamp to row 0)
    float4 fd[3];
#pragma unroll
    for (int r = 0; r < 3; ++r) {
        int mv = m[r * 3 + 1];      // <=0: 0 empty, -v occupied
        int ridx = -mv - 1;
        ridx = ridx < 0 ? 0 : ridx;
        fd[r] = feat[(size_t)ridx * 8 + cg];
    }

    float4 acc = make_float4(NEG, NEG, NEG, NEG);
#pragma unroll
    for (int r = 0; r < 3; ++r) {
        int m0 = m[r * 3 + 0];
        int m2 = m[r * 3 + 2];
        float4 f0 = sfeat[(m0 << 3) + ((cg + m0) & 7)];
        float4 f2 = sfeat[(m2 << 3) + ((cg + m2) & 7)];
        acc.x = fmaxf(acc.x, fmaxf(f0.x, f2.x));
        acc.y = fmaxf(acc.y, fmaxf(f0.y, f2.y));
        acc.z = fmaxf(acc.z, fmaxf(f0.z, f2.z));
        acc.w = fmaxf(acc.w, fmaxf(f0.w, f2.w));
        bool ok = m[r * 3 + 1] != 0;
        acc.x = fmaxf(acc.x, ok ? fd[r].x : NEG);
        acc.y = fmaxf(acc.y, ok ? fd[r].y : NEG);
        acc.z = fmaxf(acc.z, ok ? fd[r].z : NEG);
        acc.w = fmaxf(acc.w, ok ? fd[r].w : NEG);
    }

    // ---- block-uniform overflow fixup (shared cells beyond 95 slots)
    if (cnt >= MAXOCC) {
        int novf = cnt - (MAXOCC - 1);
        if (novf > OVFCAP) novf = OVFCAP;
        for (int o = 0; o < novf; ++o) {
            int cell = ovf_c[o];
            int c = cell % 65;
            if (c >= lc && c <= lc + 2) {       // this output's window
                float4 fv = feat[(size_t)ovf_i[o] * 8 + cg];
                acc.x = fmaxf(acc.x, fv.x);
                acc.y = fmaxf(acc.y, fv.y);
                acc.z = fmaxf(acc.z, fv.z);
                acc.w = fmaxf(acc.w, fv.w);
            }
        }
    }

    acc.x = isinf(acc.x) ? 0.0f : acc.x;
    acc.y = isinf(acc.y) ? 0.0f : acc.y;
    acc.z = isinf(acc.z) ? 0.0f : acc.z;
    acc.w = isinf(acc.w) ? 0.0f : acc.w;

    size_t pos = ((size_t)(b * HO + oy) * WO + ox_base + p);
    out[pos * 8 + cg] = acc;
}

extern "C" void kernel_launch(void* const* d_in, const int* in_sizes, int n_in,
                              void* d_out, int out_size, void* d_ws, size_t ws_size,
                              hipStream_t stream) {
    const float* features = (const float*)d_in[0];   // N x 32 fp32
    const int*   coors    = (const int*)d_in[1];     // N x 3 int32
    int n = in_sizes[0] / CC;                        // N = 300000

    int* grid = (int*)d_ws;                          // B*H*W int32 = 4 MiB

    // 1) zero the index grid (0xAA-poisoned every timed call)
    {
        int n4 = (BB * HH * WW) / 4;                 // 262144 int4
        int blk = 256, grd = (n4 + blk - 1) / blk;
        fill_zero_kernel<<<grd, blk, 0, stream>>>((int4*)grid, n4);
    }
    // 2) scatter indices
    {
        int blk = 256, grd = (n + blk - 1) / blk;
        scatter_idx_kernel<<<grd, blk, 0, stream>>>(coors, grid, n);
    }
    // 3) pool: 8192 blocks (32 ox x 1 oy x 8 cg per block), 8 blocks/CU
    {
        int grd = BB * HO * (WO / 32);               // 8192
        pool_kernel<<<grd, 256, 0, stream>>>((const float4*)features, grid,
                                             (float4*)d_out);
    }
}